// Round 9
// baseline (149.702 us; speedup 1.0000x reference)
//
#include <hip/hip_runtime.h>

// ---------------- types / helpers ----------------
typedef __attribute__((ext_vector_type(16))) float f32x16;
typedef __attribute__((ext_vector_type(8))) __bf16 bf16x8;
typedef __attribute__((ext_vector_type(8))) unsigned short u16x8;

__device__ __forceinline__ unsigned short f2bf(float f) {
    unsigned int u = __float_as_uint(f);
    u += 0x7fffu + ((u >> 16) & 1u);       // RTNE
    return (unsigned short)(u >> 16);
}

__device__ __forceinline__ float softplus_f(float x) {
    // max(x,0) + log2(1+exp(-|x|))*ln2 : 2 trans + 4 VALU (fma-folded)
    float e = __expf(-fabsf(x));
    return fmaf(__log2f(1.0f + e), 0.69314718056f, fmaxf(x, 0.0f));
}

typedef __attribute__((address_space(3))) void lds_void_t;
typedef __attribute__((address_space(1))) void glb_void_t;

__device__ __forceinline__ void load16_to_lds(const void* g, const void* l) {
    __builtin_amdgcn_global_load_lds((glb_void_t*)(unsigned long long)g,
                                     (lds_void_t*)(unsigned int)(unsigned long long)l,
                                     16, 0, 0);
}

// ---------------- prep: repack + tproj in one dispatch ----------------
// BOTH panels in MFMA FRAGMENT order: P[tile = row/32][c = k/8 (48)][r = row&31][8].
//  - Activation panel (B-operand): direct coalesced 1 KB wave frag-loads (R10-proven).
//  - Weight panel (A-operand): staged per-block via global_load_lds (R11 without LDS
//    failed: W=12.6MB > 4MB/XCD L2 -> HBM re-fetch). Fragment order makes the block's
//    K-slice 4 contiguous 4KB segments (coalesced staging, linear LDS dest) and the
//    per-wave ds_read_b128 contiguous 2x512B -> ZERO bank conflicts (R12 had 4-way:
//    XOR-8 only spreads 8 rows; lanes l, l+8 aliased the same 16B slot).
#define REPACK_NB 2
#define REPACK_BLOCKS 1728
#define TPROJ_BLOCKS 336      /* 84 x 4 */
#define PREP_BLOCKS (REPACK_BLOCKS + TPROJ_BLOCKS)
__global__ __launch_bounds__(256) void prep(
        const float* __restrict__ x, const float* __restrict__ iv,
        const float* __restrict__ temb,
        const float* __restrict__ Wa, const float* __restrict__ Wi,
        const float* __restrict__ Wt,
        const float* __restrict__ tW3, const float* __restrict__ tb3,
        const float* __restrict__ tW2, const float* __restrict__ tb2,
        const float* __restrict__ tW1, const float* __restrict__ tb1,
        unsigned short* __restrict__ Abf /* Wbf follows contiguously */,
        float* __restrict__ tp3T, float* __restrict__ tp2T, float* __restrict__ tp1T) {
    __shared__ float se[32 * 64];
    const int tid = threadIdx.x;

    if (blockIdx.x < TPROJ_BLOCKS) {
        // ---- tproj part: tp3T[4096][128], tp2T[1024][128], tp1T[256][128] ----
        const int bx = blockIdx.x % 84;
        const int by = blockIdx.x / 84;
        const int tbase = by * 32;
        for (int i = tid; i < 32 * 64; i += 256) se[i] = temb[tbase * 64 + i];
        __syncthreads();
        const int j = bx * 64 + (tid >> 2);
        const float* W; const float* bias; float* outp; int jl;
        if      (j < 4096) { W = tW3; bias = tb3; outp = tp3T; jl = j; }
        else if (j < 5120) { W = tW2; bias = tb2; outp = tp2T; jl = j - 4096; }
        else               { W = tW1; bias = tb1; outp = tp1T; jl = j - 5120; }
        float4 wreg[16];
        const float4* wrow = (const float4*)(W + (size_t)jl * 64);
        #pragma unroll
        for (int k = 0; k < 16; ++k) wreg[k] = wrow[k];
        const float b = bias[jl];
        #pragma unroll
        for (int s = 0; s < 8; ++s) {
            const int tl = (tid & 3) + s * 4;
            const float4* e4 = (const float4*)&se[tl * 64];
            float a = b;
            #pragma unroll
            for (int k = 0; k < 16; ++k) {
                float4 e = e4[k];
                a += wreg[k].x * e.x + wreg[k].y * e.y + wreg[k].z * e.z + wreg[k].w * e.w;
            }
            outp[(size_t)jl * 128 + tbase + tl] = a;
        }
        return;
    }

    // ---- repack part: A=[x|iv|temb], W=[Wa|Wi|Wt], BOTH fragment order ----
    const int stride = REPACK_BLOCKS * 256;
    const int tid0 = (blockIdx.x - TPROJ_BLOCKS) * 256 + tid;
    float4 f[REPACK_NB][2];
    #pragma unroll
    for (int c = 0; c < REPACK_NB; ++c) {
        const int idx = tid0 + c * stride;
        const bool isA = idx < 98304;
        const int widx = isA ? idx : idx - 98304;
        const int row = widx / 48;
        const int kk  = (widx % 48) * 8;
        const float* p0 = isA ? (x    + (size_t)row * 256) : (Wa + (size_t)row * 256);
        const float* p1 = isA ? (iv   + (size_t)row * 64)  : (Wi + (size_t)row * 64);
        const float* p2 = isA ? (temb + (size_t)(row & 127) * 64) : (Wt + (size_t)row * 64);
        const float* src = (kk < 256) ? (p0 + kk) : ((kk < 320) ? (p1 + kk - 256) : (p2 + kk - 320));
        f[c][0] = ((const float4*)src)[0];
        f[c][1] = ((const float4*)src)[1];
    }
    #pragma unroll
    for (int c = 0; c < REPACK_NB; ++c) {
        const int idx = tid0 + c * stride;
        const bool isA = idx < 98304;
        const int widx = isA ? idx : idx - 98304;
        const int row = widx / 48;
        const int ch  = widx % 48;
        // fragment-order permutation (same formula for both panels)
        const size_t dst = (size_t)(isA ? 0 : 98304) +
                           (size_t)(((row >> 5) * 48 + ch) * 32 + (row & 31));
        u16x8 o;
        o[0] = f2bf(f[c][0].x); o[1] = f2bf(f[c][0].y); o[2] = f2bf(f[c][0].z); o[3] = f2bf(f[c][0].w);
        o[4] = f2bf(f[c][1].x); o[5] = f2bf(f[c][1].y); o[6] = f2bf(f[c][1].z); o[7] = f2bf(f[c][1].w);
        *(u16x8*)(Abf + dst * 8) = o;
    }
}

// ---------------- main: transposed GEMM (M=16384 nodes, N=2048 bt, K=384) + tree ----------------
// 32x32x16 MFMA, 128x128 tile, BK=64, SINGLE-buffer 2-barrier schedule (R10's loop --
// hardware-proven; explicit dbuf measured neutral in R12, so dropped for simplicity).
// A (weights): fragment-order panel staged via global_load_lds into LDS [4 tiles][8 c][32 r][8]
//   -- coalesced staging (4 contiguous 4KB segments), linear dest, conflict-free ds_reads
//   (lanes 0-31 read 512B contiguous; lanes 32-63 the adjacent 512B).
// B (activations): direct coalesced fragment loads from global (R10).
// C-layout (m74/m101): col = lane&31 (time), row = (reg&3) + 8*(reg>>2) + 4*(lane>>5).
__global__ __launch_bounds__(256, 3)
void fused_gemm_tree(const unsigned short* __restrict__ Wf,    // A-operand, fragment order
                     const unsigned short* __restrict__ Af,    // B-operand, fragment order
                     const float* __restrict__ ba,
                     const float* __restrict__ tp3T, const float* __restrict__ tp2T,
                     const float* __restrict__ tp1T,
                     const float* __restrict__ w3, const float* __restrict__ w2,
                     const float* __restrict__ w1,
                     float* __restrict__ out) {
    __shared__ unsigned short sW[128 * 64];   // 16 KB: [4 tiles][8 chunks][32 rows][8]

    const int tid  = threadIdx.x;
    const int wave = tid >> 6;
    const int lane = tid & 63;
    const int wr = wave >> 1;          // node half: n = blockIdx.x*2 + wr
    const int wc = wave & 1;           // time half
    const int lane31 = lane & 31;
    const int h = lane >> 5;

    const int node0 = blockIdx.x * 128;
    const int m0    = blockIdx.y * 128;

    // acc init = leaf bias (ba folded into the MFMA C operand)
    f32x16 acc[2][2];
    #pragma unroll
    for (int fm = 0; fm < 2; ++fm)
        #pragma unroll
        for (int s2 = 0; s2 < 4; ++s2) {
            const float4 b4 = *(const float4*)&ba[node0 + wr * 64 + fm * 32 + 8 * s2 + 4 * h];
            #pragma unroll
            for (int l = 0; l < 4; ++l) {
                acc[fm][0][s2 * 4 + l] = ((const float*)&b4)[l];
                acc[fm][1][s2 * 4 + l] = ((const float*)&b4)[l];
            }
        }

    // A staging: block's panel = tiles [blockIdx.x*4 .. +3], fragment order.
    //   seg rr = tile rr (12288 elems each); chunk (tid>>5) of this K-step; row tid&31.
    const unsigned short* aPanel = Wf + (size_t)blockIdx.x * 4 * 12288;
    const int sOff = ((tid >> 5) * 32 + (tid & 31)) * 8;   // + rr*12288 + cbase*256

    // per-wave ds_read base: tile (wr*2+fm), chunk kc, row lane31
    const int rdBase = wr * 4096 + lane31 * 8;             // + fm*2048 + kc*256

    // B fragment base pointers: B'[tile][c][r][8]; this wave's tiles = m0/32 + wc*2 + cf
    const int mtBase = blockIdx.y * 4 + wc * 2;
    const unsigned short* bC0 = Af + (((size_t)(mtBase + 0) * 48 + h) * 32 + lane31) * 8;
    const unsigned short* bC1 = Af + (((size_t)(mtBase + 1) * 48 + h) * 32 + lane31) * 8;

    for (int it = 0; it < 6; ++it) {
        const int cbase = it * 8;
        __syncthreads();                       // all waves done reading sW (prev iter)
        // stage this K-step's A slice: 4 x 1KB coalesced wave-loads, linear LDS dest
        #pragma unroll
        for (int rr = 0; rr < 4; ++rr)
            load16_to_lds(aPanel + (size_t)rr * 12288 + (size_t)cbase * 256 + sOff,
                          &sW[(size_t)(rr * 256 + wave * 64) * 8]);
        // B fragments for THIS step (global, coalesced, drained by the same barrier)
        bf16x8 bfr[2][4];
        #pragma unroll
        for (int s = 0; s < 4; ++s) {
            bfr[0][s] = *(const bf16x8*)(bC0 + (size_t)(cbase + 2 * s) * 256);
            bfr[1][s] = *(const bf16x8*)(bC1 + (size_t)(cbase + 2 * s) * 256);
        }
        __syncthreads();                       // staging visible to all waves

        #pragma unroll
        for (int s = 0; s < 4; ++s) {          // K=16 per step
            const int kc = s * 2 + h;
            bf16x8 af[2];
            #pragma unroll
            for (int fm = 0; fm < 2; ++fm)
                af[fm] = *(const bf16x8*)&sW[rdBase + fm * 2048 + kc * 256];
            acc[0][0] = __builtin_amdgcn_mfma_f32_32x32x16_bf16(af[0], bfr[0][s], acc[0][0], 0, 0, 0);
            acc[0][1] = __builtin_amdgcn_mfma_f32_32x32x16_bf16(af[0], bfr[1][s], acc[0][1], 0, 0, 0);
            acc[1][0] = __builtin_amdgcn_mfma_f32_32x32x16_bf16(af[1], bfr[0][s], acc[1][0], 0, 0, 0);
            acc[1][1] = __builtin_amdgcn_mfma_f32_32x32x16_bf16(af[1], bfr[1][s], acc[1][1], 0, 0, 0);
        }
    }

    // ---- epilogue: softplus + 4/4/4 tree ----
    const int n = blockIdx.x * 2 + wr;
    const int t0 = wc * 64 + lane31;                   // + cf*32 -> t

    float4 w3v[2][4];
    #pragma unroll
    for (int fm = 0; fm < 2; ++fm)
        #pragma unroll
        for (int s2 = 0; s2 < 4; ++s2)
            w3v[fm][s2] = *(const float4*)&w3[n * 64 + fm * 32 + 8 * s2 + 4 * h];

    float w2v[4][2], w1v[4];                            // [i][s2b] , jj = 2*s2b + h
    #pragma unroll
    for (int i = 0; i < 4; ++i) {
        #pragma unroll
        for (int s2b = 0; s2b < 2; ++s2b)
            w2v[i][s2b] = w2[n * 16 + i * 4 + 2 * s2b + h];
        w1v[i] = w1[n * 4 + i];
    }
    float tp3v[2][2][4];                                // needed for BOTH cf (feeds shuffles)
    #pragma unroll
    for (int fm = 0; fm < 2; ++fm)
        #pragma unroll
        for (int cf = 0; cf < 2; ++cf) {
            const int t = t0 + cf * 32;
            #pragma unroll
            for (int s2 = 0; s2 < 4; ++s2) {
                const int i  = fm * 2 + (s2 >> 1);
                const int jj = 2 * (s2 & 1) + h;
                tp3v[fm][cf][s2] = tp3T[(size_t)((n * 4 + i) * 4 + jj) * 128 + t];
            }
        }
    // post-shuffle work only needs this half's own time column (cf = h)
    const int th = t0 + h * 32;
    float tp2h[2][2];                                   // [fm][b] at cf=h
    #pragma unroll
    for (int fm = 0; fm < 2; ++fm)
        #pragma unroll
        for (int b = 0; b < 2; ++b)
            tp2h[fm][b] = tp2T[(size_t)(n * 4 + fm * 2 + b) * 128 + th];
    const float tp1h = tp1T[(size_t)n * 128 + th];

    float s1h = 0.0f;
    #pragma unroll
    for (int fm = 0; fm < 2; ++fm) {
        #pragma unroll
        for (int b = 0; b < 2; ++b) {                   // i = fm*2 + b
            float cs[2];
            #pragma unroll
            for (int cf = 0; cf < 2; ++cf) {            // level-3: both cf (shuffle inputs)
                float c = 0.0f;
                #pragma unroll
                for (int s2b = 0; s2b < 2; ++s2b) {
                    const int s2 = 2 * b + s2b;
                    float p3 = 0.0f;
                    const float* wv = (const float*)&w3v[fm][s2];
                    #pragma unroll
                    for (int l = 0; l < 4; ++l) {
                        float a0 = softplus_f(acc[fm][cf][s2 * 4 + l]);   // ba already in acc
                        p3 = fmaf(a0, wv[l], p3);
                    }
                    float a3 = softplus_f(p3 + tp3v[fm][cf][s2]);
                    c = fmaf(a3, w2v[fm * 2 + b][s2b], c);
                }
                cs[cf] = c;
            }
            const float Q0 = cs[0] + __shfl_xor(cs[0], 32);   // jj-sum across halves
            const float Q1 = cs[1] + __shfl_xor(cs[1], 32);
            const float Qh = h ? Q1 : Q0;
            const float a2 = softplus_f(Qh + tp2h[fm][b]);
            s1h = fmaf(a2, w1v[fm * 2 + b], s1h);
        }
    }
    // half h stores its own t-column: 64 unique (t, n) per wave
    out[(size_t)(m0 + th) * 256 + n] = softplus_f(s1h + tp1h);
}

// ---------------- launcher ----------------
extern "C" void kernel_launch(void* const* d_in, const int* in_sizes, int n_in,
                              void* d_out, int out_size, void* d_ws, size_t ws_size,
                              hipStream_t stream) {
    const float* x    = (const float*)d_in[0];
    const float* temb = (const float*)d_in[1];
    const float* iv   = (const float*)d_in[2];
    const float* Wa   = (const float*)d_in[3];
    const float* ba   = (const float*)d_in[4];
    const float* Wt   = (const float*)d_in[5];
    const float* Wi   = (const float*)d_in[6];
    const float* w3   = (const float*)d_in[7];
    const float* tW3  = (const float*)d_in[8];
    const float* tb3  = (const float*)d_in[9];
    const float* w2   = (const float*)d_in[10];
    const float* tW2  = (const float*)d_in[11];
    const float* tb2  = (const float*)d_in[12];
    const float* w1   = (const float*)d_in[13];
    const float* tW1  = (const float*)d_in[14];
    const float* tb1  = (const float*)d_in[15];
    float* out = (float*)d_out;

    char* ws = (char*)d_ws;
    unsigned short* Abf = (unsigned short*)(ws);              //  activation panel, fragment order
    unsigned short* Wbf = (unsigned short*)(ws + 1572864);    //  weight panel, fragment order
    float* tp3T = (float*)(ws + 14155776);                    //  [4096][128]
    float* tp2T = (float*)(ws + 16252928);                    //  [1024][128]
    float* tp1T = (float*)(ws + 16777216);                    //  [256][128]

    prep<<<dim3(PREP_BLOCKS), dim3(256), 0, stream>>>(x, iv, temb, Wa, Wi, Wt,
                                                      tW3, tb3, tW2, tb2, tW1, tb1,
                                                      Abf, tp3T, tp2T, tp1T);
    fused_gemm_tree<<<dim3(128, 16), dim3(256), 0, stream>>>(Wbf, Abf, ba, tp3T, tp2T, tp1T,
                                                             w3, w2, w1, out);
}

// Round 10
// 147.928 us; speedup vs baseline: 1.0120x; 1.0120x over previous
//
#include <hip/hip_runtime.h>

// ---------------- types / helpers ----------------
typedef __attribute__((ext_vector_type(16))) float f32x16;
typedef __attribute__((ext_vector_type(8))) __bf16 bf16x8;
typedef __attribute__((ext_vector_type(8))) unsigned short u16x8;

__device__ __forceinline__ unsigned short f2bf(float f) {
    unsigned int u = __float_as_uint(f);
    u += 0x7fffu + ((u >> 16) & 1u);       // RTNE
    return (unsigned short)(u >> 16);
}

__device__ __forceinline__ float softplus_f(float x) {
    // max(x,0) + log2(1+exp(-|x|))*ln2 : 2 trans + 4 VALU (fma-folded)
    float e = __expf(-fabsf(x));
    return fmaf(__log2f(1.0f + e), 0.69314718056f, fmaxf(x, 0.0f));
}

typedef __attribute__((address_space(3))) void lds_void_t;
typedef __attribute__((address_space(1))) void glb_void_t;

__device__ __forceinline__ void load16_to_lds(const void* g, const void* l) {
    __builtin_amdgcn_global_load_lds((glb_void_t*)(unsigned long long)g,
                                     (lds_void_t*)(unsigned int)(unsigned long long)l,
                                     16, 0, 0);
}

// ---------------- prep: repack + tproj in one dispatch (unchanged from R14) ----------------
// BOTH panels in MFMA FRAGMENT order: P[tile = row/32][c = k/8 (48)][r = row&31][8].
#define REPACK_NB 2
#define REPACK_BLOCKS 1728
#define TPROJ_BLOCKS 336      /* 84 x 4 */
#define PREP_BLOCKS (REPACK_BLOCKS + TPROJ_BLOCKS)
__global__ __launch_bounds__(256) void prep(
        const float* __restrict__ x, const float* __restrict__ iv,
        const float* __restrict__ temb,
        const float* __restrict__ Wa, const float* __restrict__ Wi,
        const float* __restrict__ Wt,
        const float* __restrict__ tW3, const float* __restrict__ tb3,
        const float* __restrict__ tW2, const float* __restrict__ tb2,
        const float* __restrict__ tW1, const float* __restrict__ tb1,
        unsigned short* __restrict__ Abf /* Wbf follows contiguously */,
        float* __restrict__ tp3T, float* __restrict__ tp2T, float* __restrict__ tp1T) {
    __shared__ float se[32 * 64];
    const int tid = threadIdx.x;

    if (blockIdx.x < TPROJ_BLOCKS) {
        // ---- tproj part: tp3T[4096][128], tp2T[1024][128], tp1T[256][128] ----
        const int bx = blockIdx.x % 84;
        const int by = blockIdx.x / 84;
        const int tbase = by * 32;
        for (int i = tid; i < 32 * 64; i += 256) se[i] = temb[tbase * 64 + i];
        __syncthreads();
        const int j = bx * 64 + (tid >> 2);
        const float* W; const float* bias; float* outp; int jl;
        if      (j < 4096) { W = tW3; bias = tb3; outp = tp3T; jl = j; }
        else if (j < 5120) { W = tW2; bias = tb2; outp = tp2T; jl = j - 4096; }
        else               { W = tW1; bias = tb1; outp = tp1T; jl = j - 5120; }
        float4 wreg[16];
        const float4* wrow = (const float4*)(W + (size_t)jl * 64);
        #pragma unroll
        for (int k = 0; k < 16; ++k) wreg[k] = wrow[k];
        const float b = bias[jl];
        #pragma unroll
        for (int s = 0; s < 8; ++s) {
            const int tl = (tid & 3) + s * 4;
            const float4* e4 = (const float4*)&se[tl * 64];
            float a = b;
            #pragma unroll
            for (int k = 0; k < 16; ++k) {
                float4 e = e4[k];
                a += wreg[k].x * e.x + wreg[k].y * e.y + wreg[k].z * e.z + wreg[k].w * e.w;
            }
            outp[(size_t)jl * 128 + tbase + tl] = a;
        }
        return;
    }

    // ---- repack part: A=[x|iv|temb], W=[Wa|Wi|Wt], BOTH fragment order ----
    const int stride = REPACK_BLOCKS * 256;
    const int tid0 = (blockIdx.x - TPROJ_BLOCKS) * 256 + tid;
    float4 f[REPACK_NB][2];
    #pragma unroll
    for (int c = 0; c < REPACK_NB; ++c) {
        const int idx = tid0 + c * stride;
        const bool isA = idx < 98304;
        const int widx = isA ? idx : idx - 98304;
        const int row = widx / 48;
        const int kk  = (widx % 48) * 8;
        const float* p0 = isA ? (x    + (size_t)row * 256) : (Wa + (size_t)row * 256);
        const float* p1 = isA ? (iv   + (size_t)row * 64)  : (Wi + (size_t)row * 64);
        const float* p2 = isA ? (temb + (size_t)(row & 127) * 64) : (Wt + (size_t)row * 64);
        const float* src = (kk < 256) ? (p0 + kk) : ((kk < 320) ? (p1 + kk - 256) : (p2 + kk - 320));
        f[c][0] = ((const float4*)src)[0];
        f[c][1] = ((const float4*)src)[1];
    }
    #pragma unroll
    for (int c = 0; c < REPACK_NB; ++c) {
        const int idx = tid0 + c * stride;
        const bool isA = idx < 98304;
        const int widx = isA ? idx : idx - 98304;
        const int row = widx / 48;
        const int ch  = widx % 48;
        // fragment-order permutation (same formula for both panels)
        const size_t dst = (size_t)(isA ? 0 : 98304) +
                           (size_t)(((row >> 5) * 48 + ch) * 32 + (row & 31));
        u16x8 o;
        o[0] = f2bf(f[c][0].x); o[1] = f2bf(f[c][0].y); o[2] = f2bf(f[c][0].z); o[3] = f2bf(f[c][0].w);
        o[4] = f2bf(f[c][1].x); o[5] = f2bf(f[c][1].y); o[6] = f2bf(f[c][1].z); o[7] = f2bf(f[c][1].w);
        *(u16x8*)(Abf + dst * 8) = o;
    }
}

// ---------------- main: transposed GEMM (M=16384 nodes, N=2048 bt, K=384) + tree ----------------
// 32x32x16 MFMA, 128x128 tile. R15: BK 64 -> 128 (3 K-iterations instead of 6).
// Rationale: conflicts are 0 (R14) but time barely moved -> the barrier-drain tails
// (vmcnt(0)+s_barrier, 12 events) are the exposed cost at 2 blocks/CU. Halving the
// event count amortizes the same staged bytes over half the sync points.
// LDS 32KB single buffer (3 blocks/CU still LDS-feasible; avoids m132's 64KB trap).
// A: fragment-order panel staged via global_load_lds, LDS [4 tiles][16 c][32 r][8],
//    conflict-free contiguous ds_read_b128 (proven R14). B: direct coalesced fragment
//    loads in two 4-step halves (caps bfr register pressure at 32 VGPR).
// C-layout (m74/m101): col = lane&31 (time), row = (reg&3) + 8*(reg>>2) + 4*(lane>>5).
__global__ __launch_bounds__(256, 3)
void fused_gemm_tree(const unsigned short* __restrict__ Wf,    // A-operand, fragment order
                     const unsigned short* __restrict__ Af,    // B-operand, fragment order
                     const float* __restrict__ ba,
                     const float* __restrict__ tp3T, const float* __restrict__ tp2T,
                     const float* __restrict__ tp1T,
                     const float* __restrict__ w3, const float* __restrict__ w2,
                     const float* __restrict__ w1,
                     float* __restrict__ out) {
    __shared__ unsigned short sW[128 * 128];   // 32 KB: [4 tiles][16 chunks][32 rows][8]

    const int tid  = threadIdx.x;
    const int wave = tid >> 6;
    const int lane = tid & 63;
    const int wr = wave >> 1;          // node half: n = blockIdx.x*2 + wr
    const int wc = wave & 1;           // time half
    const int lane31 = lane & 31;
    const int h = lane >> 5;

    const int node0 = blockIdx.x * 128;
    const int m0    = blockIdx.y * 128;

    // acc init = leaf bias (ba folded into the MFMA C operand)
    f32x16 acc[2][2];
    #pragma unroll
    for (int fm = 0; fm < 2; ++fm)
        #pragma unroll
        for (int s2 = 0; s2 < 4; ++s2) {
            const float4 b4 = *(const float4*)&ba[node0 + wr * 64 + fm * 32 + 8 * s2 + 4 * h];
            #pragma unroll
            for (int l = 0; l < 4; ++l) {
                acc[fm][0][s2 * 4 + l] = ((const float*)&b4)[l];
                acc[fm][1][s2 * 4 + l] = ((const float*)&b4)[l];
            }
        }

    // A staging: block's panel = tiles [blockIdx.x*4 .. +3], fragment order (48 chunks/tile).
    const unsigned short* aPanel = Wf + (size_t)blockIdx.x * 4 * 12288;

    // per-wave ds_read base: tile (wr*2+fm), chunk kc (0..15), row lane31
    const int rdBase = wr * 8192 + lane31 * 8;             // + fm*4096 + kc*256

    // B fragment base pointers: B'[tile][c][r][8]; this wave's tiles = m0/32 + wc*2 + cf
    const int mtBase = blockIdx.y * 4 + wc * 2;
    const unsigned short* bC0 = Af + (((size_t)(mtBase + 0) * 48 + h) * 32 + lane31) * 8;
    const unsigned short* bC1 = Af + (((size_t)(mtBase + 1) * 48 + h) * 32 + lane31) * 8;

    #pragma unroll
    for (int it = 0; it < 3; ++it) {
        const int cb = it * 16;                // first global chunk of this K-step
        __syncthreads();                       // all waves done reading sW (prev iter)
        // stage this K-step's A slice: 8 wave-loads, each 2x512B contiguous source,
        // linear LDS dest (wave-uniform base + lane x 16B)
        #pragma unroll
        for (int rr = 0; rr < 8; ++rr) {
            const int p = rr * 256 + tid;      // (tile = p>>9, c = (p>>5)&15, row = p&31)
            load16_to_lds(aPanel + (size_t)(p >> 9) * 12288
                                 + (size_t)(cb + ((p >> 5) & 15)) * 256 + (p & 31) * 8,
                          &sW[(size_t)(rr * 256 + wave * 64) * 8]);
        }
        // B fragments, first half (s = 0..3)
        bf16x8 bfr[2][4];
        #pragma unroll
        for (int s = 0; s < 4; ++s) {
            bfr[0][s] = *(const bf16x8*)(bC0 + (size_t)(cb + 2 * s + h) * 256 - (size_t)h * 0);
            bfr[1][s] = *(const bf16x8*)(bC1 + (size_t)(cb + 2 * s + h) * 256 - (size_t)h * 0);
        }
        __syncthreads();                       // staging visible to all waves

        #pragma unroll
        for (int s = 0; s < 4; ++s) {          // K=16 per step, kc = 2s+h
            const int kc = s * 2 + h;
            bf16x8 af[2];
            #pragma unroll
            for (int fm = 0; fm < 2; ++fm)
                af[fm] = *(const bf16x8*)&sW[rdBase + fm * 4096 + kc * 256];
            acc[0][0] = __builtin_amdgcn_mfma_f32_32x32x16_bf16(af[0], bfr[0][s], acc[0][0], 0, 0, 0);
            acc[0][1] = __builtin_amdgcn_mfma_f32_32x32x16_bf16(af[0], bfr[1][s], acc[0][1], 0, 0, 0);
            acc[1][0] = __builtin_amdgcn_mfma_f32_32x32x16_bf16(af[1], bfr[0][s], acc[1][0], 0, 0, 0);
            acc[1][1] = __builtin_amdgcn_mfma_f32_32x32x16_bf16(af[1], bfr[1][s], acc[1][1], 0, 0, 0);
        }
        // B fragments, second half (s = 4..7); L1/L2-hot, latency hidden by ds_read+MFMA
        #pragma unroll
        for (int s = 0; s < 4; ++s) {
            bfr[0][s] = *(const bf16x8*)(bC0 + (size_t)(cb + 8 + 2 * s + h) * 256);
            bfr[1][s] = *(const bf16x8*)(bC1 + (size_t)(cb + 8 + 2 * s + h) * 256);
        }
        #pragma unroll
        for (int s = 0; s < 4; ++s) {
            const int kc = (s + 4) * 2 + h;
            bf16x8 af[2];
            #pragma unroll
            for (int fm = 0; fm < 2; ++fm)
                af[fm] = *(const bf16x8*)&sW[rdBase + fm * 4096 + kc * 256];
            acc[0][0] = __builtin_amdgcn_mfma_f32_32x32x16_bf16(af[0], bfr[0][s], acc[0][0], 0, 0, 0);
            acc[0][1] = __builtin_amdgcn_mfma_f32_32x32x16_bf16(af[0], bfr[1][s], acc[0][1], 0, 0, 0);
            acc[1][0] = __builtin_amdgcn_mfma_f32_32x32x16_bf16(af[1], bfr[0][s], acc[1][0], 0, 0, 0);
            acc[1][1] = __builtin_amdgcn_mfma_f32_32x32x16_bf16(af[1], bfr[1][s], acc[1][1], 0, 0, 0);
        }
    }

    // ---- epilogue: softplus + 4/4/4 tree (unchanged) ----
    const int n = blockIdx.x * 2 + wr;
    const int t0 = wc * 64 + lane31;                   // + cf*32 -> t

    float4 w3v[2][4];
    #pragma unroll
    for (int fm = 0; fm < 2; ++fm)
        #pragma unroll
        for (int s2 = 0; s2 < 4; ++s2)
            w3v[fm][s2] = *(const float4*)&w3[n * 64 + fm * 32 + 8 * s2 + 4 * h];

    float w2v[4][2], w1v[4];                            // [i][s2b] , jj = 2*s2b + h
    #pragma unroll
    for (int i = 0; i < 4; ++i) {
        #pragma unroll
        for (int s2b = 0; s2b < 2; ++s2b)
            w2v[i][s2b] = w2[n * 16 + i * 4 + 2 * s2b + h];
        w1v[i] = w1[n * 4 + i];
    }
    float tp3v[2][2][4];                                // needed for BOTH cf (feeds shuffles)
    #pragma unroll
    for (int fm = 0; fm < 2; ++fm)
        #pragma unroll
        for (int cf = 0; cf < 2; ++cf) {
            const int t = t0 + cf * 32;
            #pragma unroll
            for (int s2 = 0; s2 < 4; ++s2) {
                const int i  = fm * 2 + (s2 >> 1);
                const int jj = 2 * (s2 & 1) + h;
                tp3v[fm][cf][s2] = tp3T[(size_t)((n * 4 + i) * 4 + jj) * 128 + t];
            }
        }
    // post-shuffle work only needs this half's own time column (cf = h)
    const int th = t0 + h * 32;
    float tp2h[2][2];                                   // [fm][b] at cf=h
    #pragma unroll
    for (int fm = 0; fm < 2; ++fm)
        #pragma unroll
        for (int b = 0; b < 2; ++b)
            tp2h[fm][b] = tp2T[(size_t)(n * 4 + fm * 2 + b) * 128 + th];
    const float tp1h = tp1T[(size_t)n * 128 + th];

    float s1h = 0.0f;
    #pragma unroll
    for (int fm = 0; fm < 2; ++fm) {
        #pragma unroll
        for (int b = 0; b < 2; ++b) {                   // i = fm*2 + b
            float cs[2];
            #pragma unroll
            for (int cf = 0; cf < 2; ++cf) {            // level-3: both cf (shuffle inputs)
                float c = 0.0f;
                #pragma unroll
                for (int s2b = 0; s2b < 2; ++s2b) {
                    const int s2 = 2 * b + s2b;
                    float p3 = 0.0f;
                    const float* wv = (const float*)&w3v[fm][s2];
                    #pragma unroll
                    for (int l = 0; l < 4; ++l) {
                        float a0 = softplus_f(acc[fm][cf][s2 * 4 + l]);   // ba already in acc
                        p3 = fmaf(a0, wv[l], p3);
                    }
                    float a3 = softplus_f(p3 + tp3v[fm][cf][s2]);
                    c = fmaf(a3, w2v[fm * 2 + b][s2b], c);
                }
                cs[cf] = c;
            }
            const float Q0 = cs[0] + __shfl_xor(cs[0], 32);   // jj-sum across halves
            const float Q1 = cs[1] + __shfl_xor(cs[1], 32);
            const float Qh = h ? Q1 : Q0;
            const float a2 = softplus_f(Qh + tp2h[fm][b]);
            s1h = fmaf(a2, w1v[fm * 2 + b], s1h);
        }
    }
    // half h stores its own t-column: 64 unique (t, n) per wave
    out[(size_t)(m0 + th) * 256 + n] = softplus_f(s1h + tp1h);
}

// ---------------- launcher ----------------
extern "C" void kernel_launch(void* const* d_in, const int* in_sizes, int n_in,
                              void* d_out, int out_size, void* d_ws, size_t ws_size,
                              hipStream_t stream) {
    const float* x    = (const float*)d_in[0];
    const float* temb = (const float*)d_in[1];
    const float* iv   = (const float*)d_in[2];
    const float* Wa   = (const float*)d_in[3];
    const float* ba   = (const float*)d_in[4];
    const float* Wt   = (const float*)d_in[5];
    const float* Wi   = (const float*)d_in[6];
    const float* w3   = (const float*)d_in[7];
    const float* tW3  = (const float*)d_in[8];
    const float* tb3  = (const float*)d_in[9];
    const float* w2   = (const float*)d_in[10];
    const float* tW2  = (const float*)d_in[11];
    const float* tb2  = (const float*)d_in[12];
    const float* w1   = (const float*)d_in[13];
    const float* tW1  = (const float*)d_in[14];
    const float* tb1  = (const float*)d_in[15];
    float* out = (float*)d_out;

    char* ws = (char*)d_ws;
    unsigned short* Abf = (unsigned short*)(ws);              //  activation panel, fragment order
    unsigned short* Wbf = (unsigned short*)(ws + 1572864);    //  weight panel, fragment order
    float* tp3T = (float*)(ws + 14155776);                    //  [4096][128]
    float* tp2T = (float*)(ws + 16252928);                    //  [1024][128]
    float* tp1T = (float*)(ws + 16777216);                    //  [256][128]

    prep<<<dim3(PREP_BLOCKS), dim3(256), 0, stream>>>(x, iv, temb, Wa, Wi, Wt,
                                                      tW3, tb3, tW2, tb2, tW1, tb1,
                                                      Abf, tp3T, tp2T, tp1T);
    fused_gemm_tree<<<dim3(128, 16), dim3(256), 0, stream>>>(Wbf, Abf, ba, tp3T, tp2T, tp1T,
                                                             w3, w2, w1, out);
}

// Round 11
// 147.546 us; speedup vs baseline: 1.0146x; 1.0026x over previous
//
#include <hip/hip_runtime.h>

// ---------------- types / helpers ----------------
typedef __attribute__((ext_vector_type(16))) float f32x16;
typedef __attribute__((ext_vector_type(8))) __bf16 bf16x8;
typedef __attribute__((ext_vector_type(8))) unsigned short u16x8;

__device__ __forceinline__ unsigned short f2bf(float f) {
    unsigned int u = __float_as_uint(f);
    u += 0x7fffu + ((u >> 16) & 1u);       // RTNE
    return (unsigned short)(u >> 16);
}

__device__ __forceinline__ float softplus_f(float x) {
    // max(x,0) + log2(1+exp(-|x|))*ln2 : 2 trans + 4 VALU (fma-folded)
    float e = __expf(-fabsf(x));
    return fmaf(__log2f(1.0f + e), 0.69314718056f, fmaxf(x, 0.0f));
}

typedef __attribute__((address_space(3))) void lds_void_t;
typedef __attribute__((address_space(1))) void glb_void_t;

__device__ __forceinline__ void load16_to_lds(const void* g, const void* l) {
    __builtin_amdgcn_global_load_lds((glb_void_t*)(unsigned long long)g,
                                     (lds_void_t*)(unsigned int)(unsigned long long)l,
                                     16, 0, 0);
}

// ---------------- prep: repack + tproj in one dispatch (unchanged from R14) ----------------
// BOTH panels in MFMA FRAGMENT order: P[tile = row/32][c = k/8 (48)][r = row&31][8].
#define REPACK_NB 2
#define REPACK_BLOCKS 1728
#define TPROJ_BLOCKS 336      /* 84 x 4 */
#define PREP_BLOCKS (REPACK_BLOCKS + TPROJ_BLOCKS)
__global__ __launch_bounds__(256) void prep(
        const float* __restrict__ x, const float* __restrict__ iv,
        const float* __restrict__ temb,
        const float* __restrict__ Wa, const float* __restrict__ Wi,
        const float* __restrict__ Wt,
        const float* __restrict__ tW3, const float* __restrict__ tb3,
        const float* __restrict__ tW2, const float* __restrict__ tb2,
        const float* __restrict__ tW1, const float* __restrict__ tb1,
        unsigned short* __restrict__ Abf /* Wbf follows contiguously */,
        float* __restrict__ tp3T, float* __restrict__ tp2T, float* __restrict__ tp1T) {
    __shared__ float se[32 * 64];
    const int tid = threadIdx.x;

    if (blockIdx.x < TPROJ_BLOCKS) {
        // ---- tproj part: tp3T[4096][128], tp2T[1024][128], tp1T[256][128] ----
        const int bx = blockIdx.x % 84;
        const int by = blockIdx.x / 84;
        const int tbase = by * 32;
        for (int i = tid; i < 32 * 64; i += 256) se[i] = temb[tbase * 64 + i];
        __syncthreads();
        const int j = bx * 64 + (tid >> 2);
        const float* W; const float* bias; float* outp; int jl;
        if      (j < 4096) { W = tW3; bias = tb3; outp = tp3T; jl = j; }
        else if (j < 5120) { W = tW2; bias = tb2; outp = tp2T; jl = j - 4096; }
        else               { W = tW1; bias = tb1; outp = tp1T; jl = j - 5120; }
        float4 wreg[16];
        const float4* wrow = (const float4*)(W + (size_t)jl * 64);
        #pragma unroll
        for (int k = 0; k < 16; ++k) wreg[k] = wrow[k];
        const float b = bias[jl];
        #pragma unroll
        for (int s = 0; s < 8; ++s) {
            const int tl = (tid & 3) + s * 4;
            const float4* e4 = (const float4*)&se[tl * 64];
            float a = b;
            #pragma unroll
            for (int k = 0; k < 16; ++k) {
                float4 e = e4[k];
                a += wreg[k].x * e.x + wreg[k].y * e.y + wreg[k].z * e.z + wreg[k].w * e.w;
            }
            outp[(size_t)jl * 128 + tbase + tl] = a;
        }
        return;
    }

    // ---- repack part: A=[x|iv|temb], W=[Wa|Wi|Wt], BOTH fragment order ----
    const int stride = REPACK_BLOCKS * 256;
    const int tid0 = (blockIdx.x - TPROJ_BLOCKS) * 256 + tid;
    float4 f[REPACK_NB][2];
    #pragma unroll
    for (int c = 0; c < REPACK_NB; ++c) {
        const int idx = tid0 + c * stride;
        const bool isA = idx < 98304;
        const int widx = isA ? idx : idx - 98304;
        const int row = widx / 48;
        const int kk  = (widx % 48) * 8;
        const float* p0 = isA ? (x    + (size_t)row * 256) : (Wa + (size_t)row * 256);
        const float* p1 = isA ? (iv   + (size_t)row * 64)  : (Wi + (size_t)row * 64);
        const float* p2 = isA ? (temb + (size_t)(row & 127) * 64) : (Wt + (size_t)row * 64);
        const float* src = (kk < 256) ? (p0 + kk) : ((kk < 320) ? (p1 + kk - 256) : (p2 + kk - 320));
        f[c][0] = ((const float4*)src)[0];
        f[c][1] = ((const float4*)src)[1];
    }
    #pragma unroll
    for (int c = 0; c < REPACK_NB; ++c) {
        const int idx = tid0 + c * stride;
        const bool isA = idx < 98304;
        const int widx = isA ? idx : idx - 98304;
        const int row = widx / 48;
        const int ch  = widx % 48;
        // fragment-order permutation (same formula for both panels)
        const size_t dst = (size_t)(isA ? 0 : 98304) +
                           (size_t)(((row >> 5) * 48 + ch) * 32 + (row & 31));
        u16x8 o;
        o[0] = f2bf(f[c][0].x); o[1] = f2bf(f[c][0].y); o[2] = f2bf(f[c][0].z); o[3] = f2bf(f[c][0].w);
        o[4] = f2bf(f[c][1].x); o[5] = f2bf(f[c][1].y); o[6] = f2bf(f[c][1].z); o[7] = f2bf(f[c][1].w);
        *(u16x8*)(Abf + dst * 8) = o;
    }
}

// ---------------- main: transposed GEMM (M=16384 nodes, N=2048 bt, K=384) + tree ----------------
// 32x32x16 MFMA, 128x128 tile, BK=64, single-buffer 2-barrier loop (R14 body -- best
// measured: 44.4 us, 0 bank conflicts).
// R16: GRID ROLE SWAP for A-panel L2 locality. Grid = (16 time-tiles, 128 node-panels),
// blockIdx.x fastest -> the 16 consecutive blocks share ONE 96 KB A-panel slice. Per-XCD
// co-resident A working set drops ~6-9 MB (L2 thrash) -> ~3.8 MB (L2-fits), so the
// global_load_lds staging that the per-iter vmcnt(0) drain exposes becomes an L2 hit
// (~200 cyc) instead of L3 (~500+). B panel (1.5 MB) is L2-resident either way.
// A: fragment-order panel staged via global_load_lds, LDS [4 tiles][8 c][32 r][8],
//    conflict-free contiguous ds_read_b128 (R14-proven).
// B: direct coalesced fragment loads from global (R10-proven).
// C-layout (m74/m101): col = lane&31 (time), row = (reg&3) + 8*(reg>>2) + 4*(lane>>5).
__global__ __launch_bounds__(256, 3)
void fused_gemm_tree(const unsigned short* __restrict__ Wf,    // A-operand, fragment order
                     const unsigned short* __restrict__ Af,    // B-operand, fragment order
                     const float* __restrict__ ba,
                     const float* __restrict__ tp3T, const float* __restrict__ tp2T,
                     const float* __restrict__ tp1T,
                     const float* __restrict__ w3, const float* __restrict__ w2,
                     const float* __restrict__ w1,
                     float* __restrict__ out) {
    __shared__ unsigned short sW[128 * 64];   // 16 KB: [4 tiles][8 chunks][32 rows][8]

    const int tid  = threadIdx.x;
    const int wave = tid >> 6;
    const int lane = tid & 63;
    const int wr = wave >> 1;          // node half: n = blockIdx.y*2 + wr
    const int wc = wave & 1;           // time half
    const int lane31 = lane & 31;
    const int h = lane >> 5;

    const int node0 = blockIdx.y * 128;   // R16: node panel from blockIdx.y
    const int m0    = blockIdx.x * 128;   // R16: time tile from blockIdx.x (fastest)

    // acc init = leaf bias (ba folded into the MFMA C operand)
    f32x16 acc[2][2];
    #pragma unroll
    for (int fm = 0; fm < 2; ++fm)
        #pragma unroll
        for (int s2 = 0; s2 < 4; ++s2) {
            const float4 b4 = *(const float4*)&ba[node0 + wr * 64 + fm * 32 + 8 * s2 + 4 * h];
            #pragma unroll
            for (int l = 0; l < 4; ++l) {
                acc[fm][0][s2 * 4 + l] = ((const float*)&b4)[l];
                acc[fm][1][s2 * 4 + l] = ((const float*)&b4)[l];
            }
        }

    // A staging: block's panel = tiles [blockIdx.y*4 .. +3], fragment order.
    //   seg rr = tile rr (12288 elems each); chunk (tid>>5) of this K-step; row tid&31.
    const unsigned short* aPanel = Wf + (size_t)blockIdx.y * 4 * 12288;
    const int sOff = ((tid >> 5) * 32 + (tid & 31)) * 8;   // + rr*12288 + cbase*256

    // per-wave ds_read base: tile (wr*2+fm), chunk kc, row lane31
    const int rdBase = wr * 4096 + lane31 * 8;             // + fm*2048 + kc*256

    // B fragment base pointers: B'[tile][c][r][8]; this wave's tiles = m0/32 + wc*2 + cf
    const int mtBase = blockIdx.x * 4 + wc * 2;
    const unsigned short* bC0 = Af + (((size_t)(mtBase + 0) * 48 + h) * 32 + lane31) * 8;
    const unsigned short* bC1 = Af + (((size_t)(mtBase + 1) * 48 + h) * 32 + lane31) * 8;

    for (int it = 0; it < 6; ++it) {
        const int cbase = it * 8;
        __syncthreads();                       // all waves done reading sW (prev iter)
        // stage this K-step's A slice: 4 x 1KB coalesced wave-loads, linear LDS dest
        #pragma unroll
        for (int rr = 0; rr < 4; ++rr)
            load16_to_lds(aPanel + (size_t)rr * 12288 + (size_t)cbase * 256 + sOff,
                          &sW[(size_t)(rr * 256 + wave * 64) * 8]);
        // B fragments for THIS step (global, coalesced, drained by the same barrier)
        bf16x8 bfr[2][4];
        #pragma unroll
        for (int s = 0; s < 4; ++s) {
            bfr[0][s] = *(const bf16x8*)(bC0 + (size_t)(cbase + 2 * s) * 256);
            bfr[1][s] = *(const bf16x8*)(bC1 + (size_t)(cbase + 2 * s) * 256);
        }
        __syncthreads();                       // staging visible to all waves

        #pragma unroll
        for (int s = 0; s < 4; ++s) {          // K=16 per step
            const int kc = s * 2 + h;
            bf16x8 af[2];
            #pragma unroll
            for (int fm = 0; fm < 2; ++fm)
                af[fm] = *(const bf16x8*)&sW[rdBase + fm * 2048 + kc * 256];
            acc[0][0] = __builtin_amdgcn_mfma_f32_32x32x16_bf16(af[0], bfr[0][s], acc[0][0], 0, 0, 0);
            acc[0][1] = __builtin_amdgcn_mfma_f32_32x32x16_bf16(af[0], bfr[1][s], acc[0][1], 0, 0, 0);
            acc[1][0] = __builtin_amdgcn_mfma_f32_32x32x16_bf16(af[1], bfr[0][s], acc[1][0], 0, 0, 0);
            acc[1][1] = __builtin_amdgcn_mfma_f32_32x32x16_bf16(af[1], bfr[1][s], acc[1][1], 0, 0, 0);
        }
    }

    // ---- epilogue: softplus + 4/4/4 tree ----
    const int n = blockIdx.y * 2 + wr;                 // R16: node from blockIdx.y
    const int t0 = wc * 64 + lane31;                   // + cf*32 -> t

    float4 w3v[2][4];
    #pragma unroll
    for (int fm = 0; fm < 2; ++fm)
        #pragma unroll
        for (int s2 = 0; s2 < 4; ++s2)
            w3v[fm][s2] = *(const float4*)&w3[n * 64 + fm * 32 + 8 * s2 + 4 * h];

    float w2v[4][2], w1v[4];                            // [i][s2b] , jj = 2*s2b + h
    #pragma unroll
    for (int i = 0; i < 4; ++i) {
        #pragma unroll
        for (int s2b = 0; s2b < 2; ++s2b)
            w2v[i][s2b] = w2[n * 16 + i * 4 + 2 * s2b + h];
        w1v[i] = w1[n * 4 + i];
    }
    float tp3v[2][2][4];                                // needed for BOTH cf (feeds shuffles)
    #pragma unroll
    for (int fm = 0; fm < 2; ++fm)
        #pragma unroll
        for (int cf = 0; cf < 2; ++cf) {
            const int t = t0 + cf * 32;
            #pragma unroll
            for (int s2 = 0; s2 < 4; ++s2) {
                const int i  = fm * 2 + (s2 >> 1);
                const int jj = 2 * (s2 & 1) + h;
                tp3v[fm][cf][s2] = tp3T[(size_t)((n * 4 + i) * 4 + jj) * 128 + t];
            }
        }
    // post-shuffle work only needs this half's own time column (cf = h)
    const int th = t0 + h * 32;
    float tp2h[2][2];                                   // [fm][b] at cf=h
    #pragma unroll
    for (int fm = 0; fm < 2; ++fm)
        #pragma unroll
        for (int b = 0; b < 2; ++b)
            tp2h[fm][b] = tp2T[(size_t)(n * 4 + fm * 2 + b) * 128 + th];
    const float tp1h = tp1T[(size_t)n * 128 + th];

    float s1h = 0.0f;
    #pragma unroll
    for (int fm = 0; fm < 2; ++fm) {
        #pragma unroll
        for (int b = 0; b < 2; ++b) {                   // i = fm*2 + b
            float cs[2];
            #pragma unroll
            for (int cf = 0; cf < 2; ++cf) {            // level-3: both cf (shuffle inputs)
                float c = 0.0f;
                #pragma unroll
                for (int s2b = 0; s2b < 2; ++s2b) {
                    const int s2 = 2 * b + s2b;
                    float p3 = 0.0f;
                    const float* wv = (const float*)&w3v[fm][s2];
                    #pragma unroll
                    for (int l = 0; l < 4; ++l) {
                        float a0 = softplus_f(acc[fm][cf][s2 * 4 + l]);   // ba already in acc
                        p3 = fmaf(a0, wv[l], p3);
                    }
                    float a3 = softplus_f(p3 + tp3v[fm][cf][s2]);
                    c = fmaf(a3, w2v[fm * 2 + b][s2b], c);
                }
                cs[cf] = c;
            }
            const float Q0 = cs[0] + __shfl_xor(cs[0], 32);   // jj-sum across halves
            const float Q1 = cs[1] + __shfl_xor(cs[1], 32);
            const float Qh = h ? Q1 : Q0;
            const float a2 = softplus_f(Qh + tp2h[fm][b]);
            s1h = fmaf(a2, w1v[fm * 2 + b], s1h);
        }
    }
    // half h stores its own t-column: 64 unique (t, n) per wave
    out[(size_t)(m0 + th) * 256 + n] = softplus_f(s1h + tp1h);
}

// ---------------- launcher ----------------
extern "C" void kernel_launch(void* const* d_in, const int* in_sizes, int n_in,
                              void* d_out, int out_size, void* d_ws, size_t ws_size,
                              hipStream_t stream) {
    const float* x    = (const float*)d_in[0];
    const float* temb = (const float*)d_in[1];
    const float* iv   = (const float*)d_in[2];
    const float* Wa   = (const float*)d_in[3];
    const float* ba   = (const float*)d_in[4];
    const float* Wt   = (const float*)d_in[5];
    const float* Wi   = (const float*)d_in[6];
    const float* w3   = (const float*)d_in[7];
    const float* tW3  = (const float*)d_in[8];
    const float* tb3  = (const float*)d_in[9];
    const float* w2   = (const float*)d_in[10];
    const float* tW2  = (const float*)d_in[11];
    const float* tb2  = (const float*)d_in[12];
    const float* w1   = (const float*)d_in[13];
    const float* tW1  = (const float*)d_in[14];
    const float* tb1  = (const float*)d_in[15];
    float* out = (float*)d_out;

    char* ws = (char*)d_ws;
    unsigned short* Abf = (unsigned short*)(ws);              //  activation panel, fragment order
    unsigned short* Wbf = (unsigned short*)(ws + 1572864);    //  weight panel, fragment order
    float* tp3T = (float*)(ws + 14155776);                    //  [4096][128]
    float* tp2T = (float*)(ws + 16252928);                    //  [1024][128]
    float* tp1T = (float*)(ws + 16777216);                    //  [256][128]

    prep<<<dim3(PREP_BLOCKS), dim3(256), 0, stream>>>(x, iv, temb, Wa, Wi, Wt,
                                                      tW3, tb3, tW2, tb2, tW1, tb1,
                                                      Abf, tp3T, tp2T, tp1T);
    // R16: grid (time, node) -- consecutive blocks (x fastest) share one A-panel slice
    fused_gemm_tree<<<dim3(16, 128), dim3(256), 0, stream>>>(Wbf, Abf, ba, tp3T, tp2T, tp1T,
                                                             w3, w2, w1, out);
}

// Round 12
// 145.238 us; speedup vs baseline: 1.0307x; 1.0159x over previous
//
#include <hip/hip_runtime.h>

// ---------------- types / helpers ----------------
typedef __attribute__((ext_vector_type(16))) float f32x16;
typedef __attribute__((ext_vector_type(8))) __bf16 bf16x8;
typedef __attribute__((ext_vector_type(8))) unsigned short u16x8;

__device__ __forceinline__ unsigned short f2bf(float f) {
    unsigned int u = __float_as_uint(f);
    u += 0x7fffu + ((u >> 16) & 1u);       // RTNE
    return (unsigned short)(u >> 16);
}

__device__ __forceinline__ float softplus_f(float x) {
    // max(x,0) + log2(1+exp(-|x|))*ln2 : 2 trans + 4 VALU (fma-folded)
    float e = __expf(-fabsf(x));
    return fmaf(__log2f(1.0f + e), 0.69314718056f, fmaxf(x, 0.0f));
}

typedef __attribute__((address_space(3))) void lds_void_t;
typedef __attribute__((address_space(1))) void glb_void_t;

__device__ __forceinline__ void load16_to_lds(const void* g, const void* l) {
    __builtin_amdgcn_global_load_lds((glb_void_t*)(unsigned long long)g,
                                     (lds_void_t*)(unsigned int)(unsigned long long)l,
                                     16, 0, 0);
}

// ---------------- prep: repack + tproj in one dispatch ----------------
// BOTH panels in MFMA FRAGMENT order: P[tile = row/32][c = k/8 (48)][r = row&31][8].
#define REPACK_NB 2
#define REPACK_BLOCKS 1728
#define TPROJ_BLOCKS 336      /* 84 x 4 */
#define PREP_BLOCKS (REPACK_BLOCKS + TPROJ_BLOCKS)
__global__ __launch_bounds__(256) void prep(
        const float* __restrict__ x, const float* __restrict__ iv,
        const float* __restrict__ temb,
        const float* __restrict__ Wa, const float* __restrict__ Wi,
        const float* __restrict__ Wt,
        const float* __restrict__ tW3, const float* __restrict__ tb3,
        const float* __restrict__ tW2, const float* __restrict__ tb2,
        const float* __restrict__ tW1, const float* __restrict__ tb1,
        unsigned short* __restrict__ Abf /* Wbf follows contiguously */,
        float* __restrict__ tp3T, float* __restrict__ tp2T, float* __restrict__ tp1T) {
    __shared__ float se[32 * 64];
    const int tid = threadIdx.x;

    if (blockIdx.x < TPROJ_BLOCKS) {
        // ---- tproj part: tp3T[4096][128], tp2T[1024][128], tp1T[256][128] ----
        const int bx = blockIdx.x % 84;
        const int by = blockIdx.x / 84;
        const int tbase = by * 32;
        for (int i = tid; i < 32 * 64; i += 256) se[i] = temb[tbase * 64 + i];
        __syncthreads();
        const int j = bx * 64 + (tid >> 2);
        const float* W; const float* bias; float* outp; int jl;
        if      (j < 4096) { W = tW3; bias = tb3; outp = tp3T; jl = j; }
        else if (j < 5120) { W = tW2; bias = tb2; outp = tp2T; jl = j - 4096; }
        else               { W = tW1; bias = tb1; outp = tp1T; jl = j - 5120; }
        float4 wreg[16];
        const float4* wrow = (const float4*)(W + (size_t)jl * 64);
        #pragma unroll
        for (int k = 0; k < 16; ++k) wreg[k] = wrow[k];
        const float b = bias[jl];
        #pragma unroll
        for (int s = 0; s < 8; ++s) {
            const int tl = (tid & 3) + s * 4;
            const float4* e4 = (const float4*)&se[tl * 64];
            float a = b;
            #pragma unroll
            for (int k = 0; k < 16; ++k) {
                float4 e = e4[k];
                a += wreg[k].x * e.x + wreg[k].y * e.y + wreg[k].z * e.z + wreg[k].w * e.w;
            }
            outp[(size_t)jl * 128 + tbase + tl] = a;
        }
        return;
    }

    // ---- repack part: A=[x|iv|temb], W=[Wa|Wi|Wt], BOTH fragment order ----
    const int stride = REPACK_BLOCKS * 256;
    const int tid0 = (blockIdx.x - TPROJ_BLOCKS) * 256 + tid;
    float4 f[REPACK_NB][2];
    #pragma unroll
    for (int c = 0; c < REPACK_NB; ++c) {
        const int idx = tid0 + c * stride;
        const bool isA = idx < 98304;
        const int widx = isA ? idx : idx - 98304;
        const int row = widx / 48;
        const int kk  = (widx % 48) * 8;
        const float* p0 = isA ? (x    + (size_t)row * 256) : (Wa + (size_t)row * 256);
        const float* p1 = isA ? (iv   + (size_t)row * 64)  : (Wi + (size_t)row * 64);
        const float* p2 = isA ? (temb + (size_t)(row & 127) * 64) : (Wt + (size_t)row * 64);
        const float* src = (kk < 256) ? (p0 + kk) : ((kk < 320) ? (p1 + kk - 256) : (p2 + kk - 320));
        f[c][0] = ((const float4*)src)[0];
        f[c][1] = ((const float4*)src)[1];
    }
    #pragma unroll
    for (int c = 0; c < REPACK_NB; ++c) {
        const int idx = tid0 + c * stride;
        const bool isA = idx < 98304;
        const int widx = isA ? idx : idx - 98304;
        const int row = widx / 48;
        const int ch  = widx % 48;
        // fragment-order permutation (same formula for both panels)
        const size_t dst = (size_t)(isA ? 0 : 98304) +
                           (size_t)(((row >> 5) * 48 + ch) * 32 + (row & 31));
        u16x8 o;
        o[0] = f2bf(f[c][0].x); o[1] = f2bf(f[c][0].y); o[2] = f2bf(f[c][0].z); o[3] = f2bf(f[c][0].w);
        o[4] = f2bf(f[c][1].x); o[5] = f2bf(f[c][1].y); o[6] = f2bf(f[c][1].z); o[7] = f2bf(f[c][1].w);
        *(u16x8*)(Abf + dst * 8) = o;
    }
}

// ---------------- main: transposed GEMM (M=16384 nodes, N=2048 bt, K=384) + tree ----------------
// FINAL (R14 configuration -- session best: fused 44.4 us, 0 bank conflicts).
// 32x32x16 MFMA, 128x128 tile, BK=64, single-buffer 2-barrier loop.
// Grid (128 node-panels, 16 time-tiles), node fastest: panel x -> XCD x%8 pins each
// panel to ONE XCD; per-XCD A working set = 16 panels (1.5 MB) -> L2-fits; A read from
// HBM exactly once (FETCH ~13.8 MB). (R16's swapped grid put time on the XCD axis ->
// every XCD streamed all 128 panels, FETCH 61 MB, slower.)
// A (weights): fragment-order panel staged via global_load_lds, LDS [4 tiles][8 c][32 r][8]
//   -- coalesced staging, linear dest, conflict-free contiguous ds_read_b128.
// B (activations): direct coalesced 1 KB wave fragment loads from global (L2-hot).
// C-layout (m74/m101): col = lane&31 (time), row = (reg&3) + 8*(reg>>2) + 4*(lane>>5).
__global__ __launch_bounds__(256, 3)
void fused_gemm_tree(const unsigned short* __restrict__ Wf,    // A-operand, fragment order
                     const unsigned short* __restrict__ Af,    // B-operand, fragment order
                     const float* __restrict__ ba,
                     const float* __restrict__ tp3T, const float* __restrict__ tp2T,
                     const float* __restrict__ tp1T,
                     const float* __restrict__ w3, const float* __restrict__ w2,
                     const float* __restrict__ w1,
                     float* __restrict__ out) {
    __shared__ unsigned short sW[128 * 64];   // 16 KB: [4 tiles][8 chunks][32 rows][8]

    const int tid  = threadIdx.x;
    const int wave = tid >> 6;
    const int lane = tid & 63;
    const int wr = wave >> 1;          // node half: n = blockIdx.x*2 + wr
    const int wc = wave & 1;           // time half
    const int lane31 = lane & 31;
    const int h = lane >> 5;

    const int node0 = blockIdx.x * 128;
    const int m0    = blockIdx.y * 128;

    // acc init = leaf bias (ba folded into the MFMA C operand)
    f32x16 acc[2][2];
    #pragma unroll
    for (int fm = 0; fm < 2; ++fm)
        #pragma unroll
        for (int s2 = 0; s2 < 4; ++s2) {
            const float4 b4 = *(const float4*)&ba[node0 + wr * 64 + fm * 32 + 8 * s2 + 4 * h];
            #pragma unroll
            for (int l = 0; l < 4; ++l) {
                acc[fm][0][s2 * 4 + l] = ((const float*)&b4)[l];
                acc[fm][1][s2 * 4 + l] = ((const float*)&b4)[l];
            }
        }

    // A staging: block's panel = tiles [blockIdx.x*4 .. +3], fragment order.
    //   seg rr = tile rr (12288 elems each); chunk (tid>>5) of this K-step; row tid&31.
    const unsigned short* aPanel = Wf + (size_t)blockIdx.x * 4 * 12288;
    const int sOff = ((tid >> 5) * 32 + (tid & 31)) * 8;   // + rr*12288 + cbase*256

    // per-wave ds_read base: tile (wr*2+fm), chunk kc, row lane31
    const int rdBase = wr * 4096 + lane31 * 8;             // + fm*2048 + kc*256

    // B fragment base pointers: B'[tile][c][r][8]; this wave's tiles = m0/32 + wc*2 + cf
    const int mtBase = blockIdx.y * 4 + wc * 2;
    const unsigned short* bC0 = Af + (((size_t)(mtBase + 0) * 48 + h) * 32 + lane31) * 8;
    const unsigned short* bC1 = Af + (((size_t)(mtBase + 1) * 48 + h) * 32 + lane31) * 8;

    for (int it = 0; it < 6; ++it) {
        const int cbase = it * 8;
        __syncthreads();                       // all waves done reading sW (prev iter)
        // stage this K-step's A slice: 4 x 1KB coalesced wave-loads, linear LDS dest
        #pragma unroll
        for (int rr = 0; rr < 4; ++rr)
            load16_to_lds(aPanel + (size_t)rr * 12288 + (size_t)cbase * 256 + sOff,
                          &sW[(size_t)(rr * 256 + wave * 64) * 8]);
        // B fragments for THIS step (global, coalesced, drained by the same barrier)
        bf16x8 bfr[2][4];
        #pragma unroll
        for (int s = 0; s < 4; ++s) {
            bfr[0][s] = *(const bf16x8*)(bC0 + (size_t)(cbase + 2 * s) * 256);
            bfr[1][s] = *(const bf16x8*)(bC1 + (size_t)(cbase + 2 * s) * 256);
        }
        __syncthreads();                       // staging visible to all waves

        #pragma unroll
        for (int s = 0; s < 4; ++s) {          // K=16 per step
            const int kc = s * 2 + h;
            bf16x8 af[2];
            #pragma unroll
            for (int fm = 0; fm < 2; ++fm)
                af[fm] = *(const bf16x8*)&sW[rdBase + fm * 2048 + kc * 256];
            acc[0][0] = __builtin_amdgcn_mfma_f32_32x32x16_bf16(af[0], bfr[0][s], acc[0][0], 0, 0, 0);
            acc[0][1] = __builtin_amdgcn_mfma_f32_32x32x16_bf16(af[0], bfr[1][s], acc[0][1], 0, 0, 0);
            acc[1][0] = __builtin_amdgcn_mfma_f32_32x32x16_bf16(af[1], bfr[0][s], acc[1][0], 0, 0, 0);
            acc[1][1] = __builtin_amdgcn_mfma_f32_32x32x16_bf16(af[1], bfr[1][s], acc[1][1], 0, 0, 0);
        }
    }

    // ---- epilogue: softplus + 4/4/4 tree ----
    const int n = blockIdx.x * 2 + wr;
    const int t0 = wc * 64 + lane31;                   // + cf*32 -> t

    float4 w3v[2][4];
    #pragma unroll
    for (int fm = 0; fm < 2; ++fm)
        #pragma unroll
        for (int s2 = 0; s2 < 4; ++s2)
            w3v[fm][s2] = *(const float4*)&w3[n * 64 + fm * 32 + 8 * s2 + 4 * h];

    float w2v[4][2], w1v[4];                            // [i][s2b] , jj = 2*s2b + h
    #pragma unroll
    for (int i = 0; i < 4; ++i) {
        #pragma unroll
        for (int s2b = 0; s2b < 2; ++s2b)
            w2v[i][s2b] = w2[n * 16 + i * 4 + 2 * s2b + h];
        w1v[i] = w1[n * 4 + i];
    }
    float tp3v[2][2][4];                                // needed for BOTH cf (feeds shuffles)
    #pragma unroll
    for (int fm = 0; fm < 2; ++fm)
        #pragma unroll
        for (int cf = 0; cf < 2; ++cf) {
            const int t = t0 + cf * 32;
            #pragma unroll
            for (int s2 = 0; s2 < 4; ++s2) {
                const int i  = fm * 2 + (s2 >> 1);
                const int jj = 2 * (s2 & 1) + h;
                tp3v[fm][cf][s2] = tp3T[(size_t)((n * 4 + i) * 4 + jj) * 128 + t];
            }
        }
    // post-shuffle work only needs this half's own time column (cf = h)
    const int th = t0 + h * 32;
    float tp2h[2][2];                                   // [fm][b] at cf=h
    #pragma unroll
    for (int fm = 0; fm < 2; ++fm)
        #pragma unroll
        for (int b = 0; b < 2; ++b)
            tp2h[fm][b] = tp2T[(size_t)(n * 4 + fm * 2 + b) * 128 + th];
    const float tp1h = tp1T[(size_t)n * 128 + th];

    float s1h = 0.0f;
    #pragma unroll
    for (int fm = 0; fm < 2; ++fm) {
        #pragma unroll
        for (int b = 0; b < 2; ++b) {                   // i = fm*2 + b
            float cs[2];
            #pragma unroll
            for (int cf = 0; cf < 2; ++cf) {            // level-3: both cf (shuffle inputs)
                float c = 0.0f;
                #pragma unroll
                for (int s2b = 0; s2b < 2; ++s2b) {
                    const int s2 = 2 * b + s2b;
                    float p3 = 0.0f;
                    const float* wv = (const float*)&w3v[fm][s2];
                    #pragma unroll
                    for (int l = 0; l < 4; ++l) {
                        float a0 = softplus_f(acc[fm][cf][s2 * 4 + l]);   // ba already in acc
                        p3 = fmaf(a0, wv[l], p3);
                    }
                    float a3 = softplus_f(p3 + tp3v[fm][cf][s2]);
                    c = fmaf(a3, w2v[fm * 2 + b][s2b], c);
                }
                cs[cf] = c;
            }
            const float Q0 = cs[0] + __shfl_xor(cs[0], 32);   // jj-sum across halves
            const float Q1 = cs[1] + __shfl_xor(cs[1], 32);
            const float Qh = h ? Q1 : Q0;
            const float a2 = softplus_f(Qh + tp2h[fm][b]);
            s1h = fmaf(a2, w1v[fm * 2 + b], s1h);
        }
    }
    // half h stores its own t-column: 64 unique (t, n) per wave
    out[(size_t)(m0 + th) * 256 + n] = softplus_f(s1h + tp1h);
}

// ---------------- launcher ----------------
extern "C" void kernel_launch(void* const* d_in, const int* in_sizes, int n_in,
                              void* d_out, int out_size, void* d_ws, size_t ws_size,
                              hipStream_t stream) {
    const float* x    = (const float*)d_in[0];
    const float* temb = (const float*)d_in[1];
    const float* iv   = (const float*)d_in[2];
    const float* Wa   = (const float*)d_in[3];
    const float* ba   = (const float*)d_in[4];
    const float* Wt   = (const float*)d_in[5];
    const float* Wi   = (const float*)d_in[6];
    const float* w3   = (const float*)d_in[7];
    const float* tW3  = (const float*)d_in[8];
    const float* tb3  = (const float*)d_in[9];
    const float* w2   = (const float*)d_in[10];
    const float* tW2  = (const float*)d_in[11];
    const float* tb2  = (const float*)d_in[12];
    const float* w1   = (const float*)d_in[13];
    const float* tW1  = (const float*)d_in[14];
    const float* tb1  = (const float*)d_in[15];
    float* out = (float*)d_out;

    char* ws = (char*)d_ws;
    unsigned short* Abf = (unsigned short*)(ws);              //  activation panel, fragment order
    unsigned short* Wbf = (unsigned short*)(ws + 1572864);    //  weight panel, fragment order
    float* tp3T = (float*)(ws + 14155776);                    //  [4096][128]
    float* tp2T = (float*)(ws + 16252928);                    //  [1024][128]
    float* tp1T = (float*)(ws + 16777216);                    //  [256][128]

    prep<<<dim3(PREP_BLOCKS), dim3(256), 0, stream>>>(x, iv, temb, Wa, Wi, Wt,
                                                      tW3, tb3, tW2, tb2, tW1, tb1,
                                                      Abf, tp3T, tp2T, tp1T);
    fused_gemm_tree<<<dim3(128, 16), dim3(256), 0, stream>>>(Wbf, Abf, ba, tp3T, tp2T, tp1T,
                                                             w3, w2, w1, out);
}